// Round 5
// baseline (2421.716 us; speedup 1.0000x reference)
//
#include <hip/hip_runtime.h>

#define NN 100000
#define NE 1600000
#define D 128
#define NG 1024
#define SCAN_CHUNK 2048
#define NB ((NN + SCAN_CHUNK - 1) / SCAN_CHUNK)   // 49

// ---------------- degree histogram (int) ----------------
__global__ __launch_bounds__(256) void k_hist(const int* __restrict__ dst,
                                              int* __restrict__ deg) {
    int e = blockIdx.x * 256 + threadIdx.x;
    if (e < NE) atomicAdd(&deg[dst[e]], 1);
}

__global__ __launch_bounds__(256) void k_dinv(const int* __restrict__ deg,
                                              float* __restrict__ dinv) {
    int v = blockIdx.x * 256 + threadIdx.x;
    if (v < NN) dinv[v] = rsqrtf((float)(deg[v] + 1));   // +1 self-loop
}

// ---------------- exclusive scan of deg -> row_ptr ----------------
__global__ __launch_bounds__(256) void k_scanA(const int* __restrict__ deg,
                                               int* __restrict__ row_ptr,
                                               int* __restrict__ bsum) {
    __shared__ int sh[256];
    int b = blockIdx.x, tid = threadIdx.x;
    int base = b * SCAN_CHUNK + tid * 8;
    int loc[8];
    int s = 0;
#pragma unroll
    for (int j = 0; j < 8; ++j) {
        int i = base + j;
        int d = (i < NN) ? deg[i] : 0;
        loc[j] = s;
        s += d;
    }
    sh[tid] = s;
    __syncthreads();
    for (int off = 1; off < 256; off <<= 1) {
        int v = (tid >= off) ? sh[tid - off] : 0;
        __syncthreads();
        sh[tid] += v;
        __syncthreads();
    }
    int excl = (tid == 0) ? 0 : sh[tid - 1];
#pragma unroll
    for (int j = 0; j < 8; ++j) {
        int i = base + j;
        if (i < NN) row_ptr[i] = excl + loc[j];
    }
    if (tid == 255) bsum[b] = sh[255];
}

__global__ __launch_bounds__(64) void k_scanB(int* __restrict__ bsum) {
    if (threadIdx.x == 0) {
        int run = 0;
        for (int i = 0; i < NB; ++i) {
            int t = bsum[i];
            bsum[i] = run;
            run += t;
        }
    }
}

__global__ __launch_bounds__(256) void k_scanC(int* __restrict__ row_ptr,
                                               const int* __restrict__ bsum,
                                               int* __restrict__ fill) {
    int i = blockIdx.x * 256 + threadIdx.x;
    if (i < NN) {
        int r = row_ptr[i] + bsum[i / SCAN_CHUNK];
        row_ptr[i] = r;
        fill[i] = r;
    }
    if (i == 0) row_ptr[NN] = NE;
}

// ---------------- CSR fill: csr[pos] = {src, norm} ----------------
__global__ __launch_bounds__(256) void k_fill(const int* __restrict__ src,
                                              const int* __restrict__ dst,
                                              const float* __restrict__ dinv,
                                              int* __restrict__ fill,
                                              int2* __restrict__ csr) {
    int e = blockIdx.x * 256 + threadIdx.x;
    if (e >= NE) return;
    int s = src[e], d = dst[e];
    float nrm = dinv[s] * dinv[d];
    int pos = atomicAdd(&fill[d], 1);
    csr[pos] = make_int2(s, __float_as_int(nrm));
}

// ---------------- graph boundaries from sorted batch ----------------
__global__ __launch_bounds__(256) void k_bounds(const int* __restrict__ batch,
                                                int* __restrict__ gstart) {
    int g = blockIdx.x * 256 + threadIdx.x;
    if (g > NG) return;
    if (g == NG) { gstart[NG] = NN; return; }
    int lo = 0, hi = NN;
    while (lo < hi) {
        int mid = (lo + hi) >> 1;
        if (batch[mid] < g) lo = mid + 1; else hi = mid;
    }
    gstart[g] = lo;
}

// ---------------- GEMM: out[r][c] = sum_k act(in[r][k]) * W[k][c] ----------------
// 128x128 tile, K in 8 panels of 16, reg-staged double buffer (T14 split).
// 256 thr, per-thread 8x8. LDS 33KB -> 4 blocks/CU (16 waves/CU).
__global__ __launch_bounds__(256, 4) void k_gemm(const float* __restrict__ in,
                                                 const float* __restrict__ W,
                                                 const float* __restrict__ bias_in,
                                                 int relu_in,
                                                 float* __restrict__ out) {
    __shared__ float xs[2][16][132];   // [buf][k][row] transposed panel
    __shared__ float ws[2][16][128];   // [buf][k][col]

    int tid  = threadIdx.x;
    int row0 = blockIdx.x * 128;

    // staging map: x -> thread covers rows (srow, srow+64), k-span skq..skq+3
    int srow = tid >> 2;
    int skq  = (tid & 3) * 4;
    // staging map: W -> row wkr, cols wcq..wcq+7
    int wkr  = tid >> 4;
    int wcq  = (tid & 15) * 8;
    // compute map
    int tx = tid & 15, ty = tid >> 4;
    int c0 = tx * 8, r0 = ty * 8;

    float4 lx0, lx1, lw0, lw1;   // staging registers

    auto LOAD = [&](int kp) {
        int k0 = kp * 16;
        int rg0 = row0 + srow;       if (rg0 >= NN) rg0 = NN - 1;
        int rg1 = row0 + srow + 64;  if (rg1 >= NN) rg1 = NN - 1;
        lx0 = *(const float4*)(in + (size_t)rg0 * D + k0 + skq);
        lx1 = *(const float4*)(in + (size_t)rg1 * D + k0 + skq);
        lw0 = *(const float4*)(W + (size_t)(k0 + wkr) * D + wcq);
        lw1 = *(const float4*)(W + (size_t)(k0 + wkr) * D + wcq + 4);
        if (relu_in) {
            int kk = (kp * 16) + skq;
            float4 bb = *(const float4*)(bias_in + kk);
            lx0.x = fmaxf(lx0.x + bb.x, 0.f); lx0.y = fmaxf(lx0.y + bb.y, 0.f);
            lx0.z = fmaxf(lx0.z + bb.z, 0.f); lx0.w = fmaxf(lx0.w + bb.w, 0.f);
            lx1.x = fmaxf(lx1.x + bb.x, 0.f); lx1.y = fmaxf(lx1.y + bb.y, 0.f);
            lx1.z = fmaxf(lx1.z + bb.z, 0.f); lx1.w = fmaxf(lx1.w + bb.w, 0.f);
        }
    };
    auto WRITE = [&](int buf) {
        xs[buf][skq + 0][srow] = lx0.x;
        xs[buf][skq + 1][srow] = lx0.y;
        xs[buf][skq + 2][srow] = lx0.z;
        xs[buf][skq + 3][srow] = lx0.w;
        xs[buf][skq + 0][srow + 64] = lx1.x;
        xs[buf][skq + 1][srow + 64] = lx1.y;
        xs[buf][skq + 2][srow + 64] = lx1.z;
        xs[buf][skq + 3][srow + 64] = lx1.w;
        *(float4*)&ws[buf][wkr][wcq]     = lw0;
        *(float4*)&ws[buf][wkr][wcq + 4] = lw1;
    };

    float acc[8][8] = {};

    LOAD(0);
    WRITE(0);
    __syncthreads();

    for (int kp = 0; kp < 8; ++kp) {
        int cur = kp & 1;
        if (kp < 7) LOAD(kp + 1);          // global loads in flight over compute
#pragma unroll
        for (int kk = 0; kk < 16; ++kk) {
            float4 xa = *(const float4*)&xs[cur][kk][r0];
            float4 xb = *(const float4*)&xs[cur][kk][r0 + 4];
            float4 wa = *(const float4*)&ws[cur][kk][c0];
            float4 wb = *(const float4*)&ws[cur][kk][c0 + 4];
            float xv[8] = {xa.x, xa.y, xa.z, xa.w, xb.x, xb.y, xb.z, xb.w};
            float wv[8] = {wa.x, wa.y, wa.z, wa.w, wb.x, wb.y, wb.z, wb.w};
#pragma unroll
            for (int i = 0; i < 8; ++i)
#pragma unroll
                for (int j = 0; j < 8; ++j)
                    acc[i][j] += xv[i] * wv[j];
        }
        if (kp < 7) {
            __syncthreads();               // all reads of buf^1 (prev panel) done
            WRITE(cur ^ 1);
            __syncthreads();
        }
    }

#pragma unroll
    for (int i = 0; i < 8; ++i) {
        int rg = row0 + r0 + i;
        if (rg < NN) {
            float4 o0 = make_float4(acc[i][0], acc[i][1], acc[i][2], acc[i][3]);
            float4 o1 = make_float4(acc[i][4], acc[i][5], acc[i][6], acc[i][7]);
            *(float4*)(out + (size_t)rg * D + c0)     = o0;
            *(float4*)(out + (size_t)rg * D + c0 + 4) = o1;
        }
    }
}

// ---------------- gather: agg[v] = h[v]*dinv[v]^2 + sum_in h[s]*norm ----------------
// round-3 structure (32-lane group per node), 4-deep independent h loads
__global__ __launch_bounds__(256) void k_gather(const float* __restrict__ h,
                                                const int* __restrict__ row_ptr,
                                                const int2* __restrict__ csr,
                                                const float* __restrict__ dinv,
                                                float* __restrict__ agg) {
    int t = blockIdx.x * 256 + threadIdx.x;   // NN*32 threads
    int v = t >> 5;
    if (v >= NN) return;
    int c = (t & 31) * 4;

    float di = dinv[v];
    float sl = di * di;
    float4 acc = *(const float4*)(h + (size_t)v * D + c);
    acc.x *= sl; acc.y *= sl; acc.z *= sl; acc.w *= sl;

    int p   = row_ptr[v];
    int end = row_ptr[v + 1];
    for (; p + 3 < end; p += 4) {
        int2 e0 = csr[p], e1 = csr[p + 1], e2 = csr[p + 2], e3 = csr[p + 3];
        float n0 = __int_as_float(e0.y);
        float n1 = __int_as_float(e1.y);
        float n2 = __int_as_float(e2.y);
        float n3 = __int_as_float(e3.y);
        float4 h0 = *(const float4*)(h + (size_t)e0.x * D + c);
        float4 h1 = *(const float4*)(h + (size_t)e1.x * D + c);
        float4 h2 = *(const float4*)(h + (size_t)e2.x * D + c);
        float4 h3 = *(const float4*)(h + (size_t)e3.x * D + c);
        acc.x += h0.x * n0; acc.y += h0.y * n0; acc.z += h0.z * n0; acc.w += h0.w * n0;
        acc.x += h1.x * n1; acc.y += h1.y * n1; acc.z += h1.z * n1; acc.w += h1.w * n1;
        acc.x += h2.x * n2; acc.y += h2.y * n2; acc.z += h2.z * n2; acc.w += h2.w * n2;
        acc.x += h3.x * n3; acc.y += h3.y * n3; acc.z += h3.z * n3; acc.w += h3.w * n3;
    }
    for (; p < end; ++p) {
        int2 e0 = csr[p];
        float n0 = __int_as_float(e0.y);
        float4 h0 = *(const float4*)(h + (size_t)e0.x * D + c);
        acc.x += h0.x * n0; acc.y += h0.y * n0; acc.z += h0.z * n0; acc.w += h0.w * n0;
    }
    *(float4*)(agg + (size_t)v * D + c) = acc;
}

// ---------------- fused pool + classifier (block per graph) ----------------
__global__ __launch_bounds__(128) void k_poolcls(const float* __restrict__ agg,
                                                 const float* __restrict__ b2,
                                                 const int* __restrict__ gstart,
                                                 const float* __restrict__ Wc,
                                                 const float* __restrict__ bc,
                                                 float* __restrict__ out) {
    int g = blockIdx.x;
    int c = threadIdx.x;
    int v0 = gstart[g], v1 = gstart[g + 1];
    float bb = b2[c];
    float acc = 0.f;
    int v = v0;
    for (; v + 3 < v1; v += 4) {
        float x0 = agg[(size_t)(v + 0) * D + c];
        float x1 = agg[(size_t)(v + 1) * D + c];
        float x2 = agg[(size_t)(v + 2) * D + c];
        float x3 = agg[(size_t)(v + 3) * D + c];
        acc += fmaxf(x0 + bb, 0.f) + fmaxf(x1 + bb, 0.f)
             + fmaxf(x2 + bb, 0.f) + fmaxf(x3 + bb, 0.f);
    }
    for (; v < v1; ++v)
        acc += fmaxf(agg[(size_t)v * D + c] + bb, 0.f);

    float inv = 1.0f / fmaxf((float)(v1 - v0), 1.0f);
    float pv = acc * inv;

    __shared__ float red[2][128];
    red[0][c] = pv * Wc[c * 2 + 0];
    red[1][c] = pv * Wc[c * 2 + 1];
    __syncthreads();
    if (c < 64) {
        float s = red[0][c] + red[0][c + 64];
        for (int off = 32; off; off >>= 1) s += __shfl_down(s, off);
        if (c == 0) out[g * 2 + 0] = s + bc[0];
    } else {
        int l = c - 64;
        float s = red[1][l] + red[1][l + 64];
        for (int off = 32; off; off >>= 1) s += __shfl_down(s, off);
        if (l == 0) out[g * 2 + 1] = s + bc[1];
    }
}

extern "C" void kernel_launch(void* const* d_in, const int* in_sizes, int n_in,
                              void* d_out, int out_size, void* d_ws, size_t ws_size,
                              hipStream_t stream) {
    const float* x     = (const float*)d_in[0];
    const int*   ei    = (const int*)d_in[1];
    const int*   batch = (const int*)d_in[2];
    const float* W1    = (const float*)d_in[3];
    const float* b1    = (const float*)d_in[4];
    const float* W2    = (const float*)d_in[5];
    const float* b2    = (const float*)d_in[6];
    const float* Wc    = (const float*)d_in[7];
    const float* bc    = (const float*)d_in[8];
    float* out = (float*)d_out;

    const int* src = ei;            // edge_index[0]
    const int* dst = ei + NE;       // edge_index[1]

    char* p = (char*)d_ws;
    int*   deg_i   = (int*)p;    p += 100352 * 4;
    float* dinv    = (float*)p;  p += 100352 * 4;
    int*   row_ptr = (int*)p;    p += 100352 * 4;   // NN+1 fits
    int*   fillc   = (int*)p;    p += 100352 * 4;
    int*   bsum    = (int*)p;    p += 256 * 4;
    int*   gstart  = (int*)p;    p += 1056 * 4;     // NG+1
    int2*  csr     = (int2*)p;   p += (size_t)NE * 8;
    float* bufA    = (float*)p;  p += (size_t)NN * D * 4;
    float* bufB    = (float*)p;  p += (size_t)NN * D * 4;

    hipMemsetAsync(deg_i, 0, 100352 * 4, stream);

    // CSR build + graph bounds
    k_hist  <<<(NE + 255) / 256, 256, 0, stream>>>(dst, deg_i);
    k_dinv  <<<(NN + 255) / 256, 256, 0, stream>>>(deg_i, dinv);
    k_scanA <<<NB, 256, 0, stream>>>(deg_i, row_ptr, bsum);
    k_scanB <<<1, 64, 0, stream>>>(bsum);
    k_scanC <<<(NN + 255) / 256, 256, 0, stream>>>(row_ptr, bsum, fillc);
    k_fill  <<<(NE + 255) / 256, 256, 0, stream>>>(src, dst, dinv, fillc, csr);
    k_bounds<<<(NG + 256) / 256, 256, 0, stream>>>(batch, gstart);

    // layer 1
    k_gemm  <<<(NN + 127) / 128, 256, 0, stream>>>(x, W1, nullptr, 0, bufA);
    k_gather<<<NN * 32 / 256, 256, 0, stream>>>(bufA, row_ptr, csr, dinv, bufB);

    // layer 2 (bias1+relu fused into gemm load)
    k_gemm  <<<(NN + 127) / 128, 256, 0, stream>>>(bufB, W2, b1, 1, bufA);
    k_gather<<<NN * 32 / 256, 256, 0, stream>>>(bufA, row_ptr, csr, dinv, bufB);

    // fused pooling (bias2+relu) + classifier
    k_poolcls<<<NG, 128, 0, stream>>>(bufB, b2, gstart, Wc, bc, out);
}

// Round 6
// 519.936 us; speedup vs baseline: 4.6577x; 4.6577x over previous
//
#include <hip/hip_runtime.h>

#define NN 100000
#define NE 1600000
#define D 128
#define NG 1024
#define SCAN_CHUNK 2048
#define NB ((NN + SCAN_CHUNK - 1) / SCAN_CHUNK)   // 49

// ---------------- degree histogram (int) ----------------
__global__ __launch_bounds__(256) void k_hist(const int* __restrict__ dst,
                                              int* __restrict__ deg) {
    int e = blockIdx.x * 256 + threadIdx.x;
    if (e < NE) atomicAdd(&deg[dst[e]], 1);
}

__global__ __launch_bounds__(256) void k_dinv(const int* __restrict__ deg,
                                              float* __restrict__ dinv) {
    int v = blockIdx.x * 256 + threadIdx.x;
    if (v < NN) dinv[v] = rsqrtf((float)(deg[v] + 1));   // +1 self-loop
}

// ---------------- exclusive scan of deg -> row_ptr ----------------
__global__ __launch_bounds__(256) void k_scanA(const int* __restrict__ deg,
                                               int* __restrict__ row_ptr,
                                               int* __restrict__ bsum) {
    __shared__ int sh[256];
    int b = blockIdx.x, tid = threadIdx.x;
    int base = b * SCAN_CHUNK + tid * 8;
    int loc[8];
    int s = 0;
#pragma unroll
    for (int j = 0; j < 8; ++j) {
        int i = base + j;
        int d = (i < NN) ? deg[i] : 0;
        loc[j] = s;
        s += d;
    }
    sh[tid] = s;
    __syncthreads();
    for (int off = 1; off < 256; off <<= 1) {
        int v = (tid >= off) ? sh[tid - off] : 0;
        __syncthreads();
        sh[tid] += v;
        __syncthreads();
    }
    int excl = (tid == 0) ? 0 : sh[tid - 1];
#pragma unroll
    for (int j = 0; j < 8; ++j) {
        int i = base + j;
        if (i < NN) row_ptr[i] = excl + loc[j];
    }
    if (tid == 255) bsum[b] = sh[255];
}

__global__ __launch_bounds__(64) void k_scanB(int* __restrict__ bsum) {
    if (threadIdx.x == 0) {
        int run = 0;
        for (int i = 0; i < NB; ++i) {
            int t = bsum[i];
            bsum[i] = run;
            run += t;
        }
    }
}

__global__ __launch_bounds__(256) void k_scanC(int* __restrict__ row_ptr,
                                               const int* __restrict__ bsum,
                                               int* __restrict__ fill) {
    int i = blockIdx.x * 256 + threadIdx.x;
    if (i < NN) {
        int r = row_ptr[i] + bsum[i / SCAN_CHUNK];
        row_ptr[i] = r;
        fill[i] = r;
    }
    if (i == 0) row_ptr[NN] = NE;
}

// ---------------- CSR fill: csr[pos] = {src, norm} ----------------
__global__ __launch_bounds__(256) void k_fill(const int* __restrict__ src,
                                              const int* __restrict__ dst,
                                              const float* __restrict__ dinv,
                                              int* __restrict__ fill,
                                              int2* __restrict__ csr) {
    int e = blockIdx.x * 256 + threadIdx.x;
    if (e >= NE) return;
    int s = src[e], d = dst[e];
    float nrm = dinv[s] * dinv[d];
    int pos = atomicAdd(&fill[d], 1);
    csr[pos] = make_int2(s, __float_as_int(nrm));
}

// ---------------- graph boundaries from sorted batch ----------------
__global__ __launch_bounds__(256) void k_bounds(const int* __restrict__ batch,
                                                int* __restrict__ gstart) {
    int g = blockIdx.x * 256 + threadIdx.x;
    if (g > NG) return;
    if (g == NG) { gstart[NG] = NN; return; }
    int lo = 0, hi = NN;
    while (lo < hi) {
        int mid = (lo + hi) >> 1;
        if (batch[mid] < g) lo = mid + 1; else hi = mid;
    }
    gstart[g] = lo;
}

// ---------------- GEMM: out[r][c] = sum_k act(in[r][k]) * W[k][c] ----------------
// 64x128 tile, K in 8 double-buffered panels of 16. 256 thr, per-thread 4x8
// (32 acc VGPRs -> no spill). LDS 24.7KB -> ~6 blocks/CU.
__global__ __launch_bounds__(256) void k_gemm(const float* __restrict__ in,
                                              const float* __restrict__ W,
                                              const float* __restrict__ bias_in,
                                              int relu_in,
                                              float* __restrict__ out) {
    __shared__ float xs[2][16][68];    // [buf][k][row] transposed panel, 2-way max
    __shared__ float ws[2][16][128];   // [buf][k][col], lane-sequential float4s

    int tid  = threadIdx.x;
    int row0 = blockIdx.x * 64;

    // x staging: row = tid>>2 (0..63), k-quad = (tid&3)*4
    int srow = tid >> 2;
    int skq  = (tid & 3) * 4;
    // W staging: two float4s, flat-sequential: k-row tid>>5 and 8+(tid>>5), col (tid&31)*4
    int wkr  = tid >> 5;
    int wcq  = (tid & 31) * 4;
    // compute: tx = col group (0..15), ty = row group (0..15)
    int tx = tid & 15, ty = tid >> 4;
    int r0 = ty * 4, c0 = tx * 4;      // cols c0 and c0+64

    float4 lx, lw0, lw1;

    auto LOAD = [&](int kp) {
        int k0 = kp * 16;
        int rg = row0 + srow; if (rg >= NN) rg = NN - 1;
        lx  = *(const float4*)(in + (size_t)rg * D + k0 + skq);
        lw0 = *(const float4*)(W + (size_t)(k0 + wkr) * D + wcq);
        lw1 = *(const float4*)(W + (size_t)(k0 + 8 + wkr) * D + wcq);
        if (relu_in) {
            float4 bb = *(const float4*)(bias_in + k0 + skq);
            lx.x = fmaxf(lx.x + bb.x, 0.f);
            lx.y = fmaxf(lx.y + bb.y, 0.f);
            lx.z = fmaxf(lx.z + bb.z, 0.f);
            lx.w = fmaxf(lx.w + bb.w, 0.f);
        }
    };
    auto WRITE = [&](int buf) {
        xs[buf][skq + 0][srow] = lx.x;
        xs[buf][skq + 1][srow] = lx.y;
        xs[buf][skq + 2][srow] = lx.z;
        xs[buf][skq + 3][srow] = lx.w;
        *(float4*)&ws[buf][wkr][wcq]     = lw0;
        *(float4*)&ws[buf][wkr + 8][wcq] = lw1;
    };

    float acc[4][8] = {};

    LOAD(0);
    WRITE(0);
    __syncthreads();

    for (int kp = 0; kp < 8; ++kp) {
        int cur = kp & 1;
        if (kp < 7) LOAD(kp + 1);      // global loads in flight over compute
#pragma unroll
        for (int kk = 0; kk < 16; ++kk) {
            float4 xa = *(const float4*)&xs[cur][kk][r0];
            float4 wa = *(const float4*)&ws[cur][kk][c0];
            float4 wb = *(const float4*)&ws[cur][kk][c0 + 64];
            float xv[4] = {xa.x, xa.y, xa.z, xa.w};
            float wv[8] = {wa.x, wa.y, wa.z, wa.w, wb.x, wb.y, wb.z, wb.w};
#pragma unroll
            for (int i = 0; i < 4; ++i)
#pragma unroll
                for (int j = 0; j < 8; ++j)
                    acc[i][j] += xv[i] * wv[j];
        }
        if (kp < 7) {
            __syncthreads();           // readers of buf^1 done
            WRITE(cur ^ 1);
            __syncthreads();
        }
    }

#pragma unroll
    for (int i = 0; i < 4; ++i) {
        int rg = row0 + r0 + i;
        if (rg < NN) {
            *(float4*)(out + (size_t)rg * D + c0) =
                make_float4(acc[i][0], acc[i][1], acc[i][2], acc[i][3]);
            *(float4*)(out + (size_t)rg * D + c0 + 64) =
                make_float4(acc[i][4], acc[i][5], acc[i][6], acc[i][7]);
        }
    }
}

// ---------------- gather: agg[v] = h[v]*dinv[v]^2 + sum_in h[s]*norm ----------------
__global__ __launch_bounds__(256) void k_gather(const float* __restrict__ h,
                                                const int* __restrict__ row_ptr,
                                                const int2* __restrict__ csr,
                                                const float* __restrict__ dinv,
                                                float* __restrict__ agg) {
    int t = blockIdx.x * 256 + threadIdx.x;   // NN*32 threads
    int v = t >> 5;
    if (v >= NN) return;
    int c = (t & 31) * 4;

    float di = dinv[v];
    float sl = di * di;
    float4 acc = *(const float4*)(h + (size_t)v * D + c);
    acc.x *= sl; acc.y *= sl; acc.z *= sl; acc.w *= sl;

    int p   = row_ptr[v];
    int end = row_ptr[v + 1];
    for (; p + 3 < end; p += 4) {
        int2 e0 = csr[p], e1 = csr[p + 1], e2 = csr[p + 2], e3 = csr[p + 3];
        float n0 = __int_as_float(e0.y);
        float n1 = __int_as_float(e1.y);
        float n2 = __int_as_float(e2.y);
        float n3 = __int_as_float(e3.y);
        float4 h0 = *(const float4*)(h + (size_t)e0.x * D + c);
        float4 h1 = *(const float4*)(h + (size_t)e1.x * D + c);
        float4 h2 = *(const float4*)(h + (size_t)e2.x * D + c);
        float4 h3 = *(const float4*)(h + (size_t)e3.x * D + c);
        acc.x += h0.x * n0; acc.y += h0.y * n0; acc.z += h0.z * n0; acc.w += h0.w * n0;
        acc.x += h1.x * n1; acc.y += h1.y * n1; acc.z += h1.z * n1; acc.w += h1.w * n1;
        acc.x += h2.x * n2; acc.y += h2.y * n2; acc.z += h2.z * n2; acc.w += h2.w * n2;
        acc.x += h3.x * n3; acc.y += h3.y * n3; acc.z += h3.z * n3; acc.w += h3.w * n3;
    }
    for (; p < end; ++p) {
        int2 e0 = csr[p];
        float n0 = __int_as_float(e0.y);
        float4 h0 = *(const float4*)(h + (size_t)e0.x * D + c);
        acc.x += h0.x * n0; acc.y += h0.y * n0; acc.z += h0.z * n0; acc.w += h0.w * n0;
    }
    *(float4*)(agg + (size_t)v * D + c) = acc;
}

// ---------------- fused pool + classifier (block per graph) ----------------
__global__ __launch_bounds__(128) void k_poolcls(const float* __restrict__ agg,
                                                 const float* __restrict__ b2,
                                                 const int* __restrict__ gstart,
                                                 const float* __restrict__ Wc,
                                                 const float* __restrict__ bc,
                                                 float* __restrict__ out) {
    int g = blockIdx.x;
    int c = threadIdx.x;
    int v0 = gstart[g], v1 = gstart[g + 1];
    float bb = b2[c];
    float acc = 0.f;
    int v = v0;
    for (; v + 3 < v1; v += 4) {
        float x0 = agg[(size_t)(v + 0) * D + c];
        float x1 = agg[(size_t)(v + 1) * D + c];
        float x2 = agg[(size_t)(v + 2) * D + c];
        float x3 = agg[(size_t)(v + 3) * D + c];
        acc += fmaxf(x0 + bb, 0.f) + fmaxf(x1 + bb, 0.f)
             + fmaxf(x2 + bb, 0.f) + fmaxf(x3 + bb, 0.f);
    }
    for (; v < v1; ++v)
        acc += fmaxf(agg[(size_t)v * D + c] + bb, 0.f);

    float inv = 1.0f / fmaxf((float)(v1 - v0), 1.0f);
    float pv = acc * inv;

    __shared__ float red[2][128];
    red[0][c] = pv * Wc[c * 2 + 0];
    red[1][c] = pv * Wc[c * 2 + 1];
    __syncthreads();
    if (c < 64) {
        float s = red[0][c] + red[0][c + 64];
        for (int off = 32; off; off >>= 1) s += __shfl_down(s, off);
        if (c == 0) out[g * 2 + 0] = s + bc[0];
    } else {
        int l = c - 64;
        float s = red[1][l] + red[1][l + 64];
        for (int off = 32; off; off >>= 1) s += __shfl_down(s, off);
        if (l == 0) out[g * 2 + 1] = s + bc[1];
    }
}

extern "C" void kernel_launch(void* const* d_in, const int* in_sizes, int n_in,
                              void* d_out, int out_size, void* d_ws, size_t ws_size,
                              hipStream_t stream) {
    const float* x     = (const float*)d_in[0];
    const int*   ei    = (const int*)d_in[1];
    const int*   batch = (const int*)d_in[2];
    const float* W1    = (const float*)d_in[3];
    const float* b1    = (const float*)d_in[4];
    const float* W2    = (const float*)d_in[5];
    const float* b2    = (const float*)d_in[6];
    const float* Wc    = (const float*)d_in[7];
    const float* bc    = (const float*)d_in[8];
    float* out = (float*)d_out;

    const int* src = ei;            // edge_index[0]
    const int* dst = ei + NE;       // edge_index[1]

    char* p = (char*)d_ws;
    int*   deg_i   = (int*)p;    p += 100352 * 4;
    float* dinv    = (float*)p;  p += 100352 * 4;
    int*   row_ptr = (int*)p;    p += 100352 * 4;   // NN+1 fits
    int*   fillc   = (int*)p;    p += 100352 * 4;
    int*   bsum    = (int*)p;    p += 256 * 4;
    int*   gstart  = (int*)p;    p += 1056 * 4;     // NG+1
    int2*  csr     = (int2*)p;   p += (size_t)NE * 8;
    float* bufA    = (float*)p;  p += (size_t)NN * D * 4;
    float* bufB    = (float*)p;  p += (size_t)NN * D * 4;

    hipMemsetAsync(deg_i, 0, 100352 * 4, stream);

    // CSR build + graph bounds
    k_hist  <<<(NE + 255) / 256, 256, 0, stream>>>(dst, deg_i);
    k_dinv  <<<(NN + 255) / 256, 256, 0, stream>>>(deg_i, dinv);
    k_scanA <<<NB, 256, 0, stream>>>(deg_i, row_ptr, bsum);
    k_scanB <<<1, 64, 0, stream>>>(bsum);
    k_scanC <<<(NN + 255) / 256, 256, 0, stream>>>(row_ptr, bsum, fillc);
    k_fill  <<<(NE + 255) / 256, 256, 0, stream>>>(src, dst, dinv, fillc, csr);
    k_bounds<<<(NG + 256) / 256, 256, 0, stream>>>(batch, gstart);

    // layer 1
    k_gemm  <<<(NN + 63) / 64, 256, 0, stream>>>(x, W1, nullptr, 0, bufA);
    k_gather<<<NN * 32 / 256, 256, 0, stream>>>(bufA, row_ptr, csr, dinv, bufB);

    // layer 2 (bias1+relu fused into gemm load)
    k_gemm  <<<(NN + 63) / 64, 256, 0, stream>>>(bufB, W2, b1, 1, bufA);
    k_gather<<<NN * 32 / 256, 256, 0, stream>>>(bufA, row_ptr, csr, dinv, bufB);

    // fused pooling (bias2+relu) + classifier
    k_poolcls<<<NG, 128, 0, stream>>>(bufB, b2, gstart, Wc, bc, out);
}

// Round 7
// 507.795 us; speedup vs baseline: 4.7691x; 1.0239x over previous
//
#include <hip/hip_runtime.h>

#define NN 100000
#define NE 1600000
#define D 128
#define NG 1024
#define SCAN_CHUNK 2048
#define NB ((NN + SCAN_CHUNK - 1) / SCAN_CHUNK)   // 49
#define GEMM_BLKS ((NN + 63) / 64)                // 1563
#define HIST_BLKS ((NE + 255) / 256)              // 6250
#define BOUNDS_BLKS 5                             // 5*256 >= NG+1

// ---------------- GEMM body: out[r][c] = sum_k act(in[r][k]) * W[k][c] ----------------
// 64x128 tile, K in 8 double-buffered panels of 16. 256 thr, per-thread 4x8.
__device__ __forceinline__ void gemm_body(const float* __restrict__ in,
                                          const float* __restrict__ W,
                                          const float* __restrict__ bias_in,
                                          int relu_in,
                                          float* __restrict__ out,
                                          int blk) {
    __shared__ float xs[2][16][68];    // [buf][k][row] transposed panel (2-way max)
    __shared__ float ws[2][16][128];   // [buf][k][col] lane-sequential float4s

    int tid  = threadIdx.x;
    int row0 = blk * 64;

    int srow = tid >> 2;               // x staging row 0..63
    int skq  = (tid & 3) * 4;          // k-quad
    int wkr  = tid >> 5;               // W staging k-row
    int wcq  = (tid & 31) * 4;         // W col quad
    int tx = tid & 15, ty = tid >> 4;
    int r0 = ty * 4, c0 = tx * 4;      // cols c0 and c0+64

    float4 lx, lw0, lw1;

    auto LOAD = [&](int kp) {
        int k0 = kp * 16;
        int rg = row0 + srow; if (rg >= NN) rg = NN - 1;
        lx  = *(const float4*)(in + (size_t)rg * D + k0 + skq);
        lw0 = *(const float4*)(W + (size_t)(k0 + wkr) * D + wcq);
        lw1 = *(const float4*)(W + (size_t)(k0 + 8 + wkr) * D + wcq);
        if (relu_in) {
            float4 bb = *(const float4*)(bias_in + k0 + skq);
            lx.x = fmaxf(lx.x + bb.x, 0.f);
            lx.y = fmaxf(lx.y + bb.y, 0.f);
            lx.z = fmaxf(lx.z + bb.z, 0.f);
            lx.w = fmaxf(lx.w + bb.w, 0.f);
        }
    };
    auto WRITE = [&](int buf) {
        xs[buf][skq + 0][srow] = lx.x;
        xs[buf][skq + 1][srow] = lx.y;
        xs[buf][skq + 2][srow] = lx.z;
        xs[buf][skq + 3][srow] = lx.w;
        *(float4*)&ws[buf][wkr][wcq]     = lw0;
        *(float4*)&ws[buf][wkr + 8][wcq] = lw1;
    };

    float acc[4][8] = {};

    LOAD(0);
    WRITE(0);
    __syncthreads();

    for (int kp = 0; kp < 8; ++kp) {
        int cur = kp & 1;
        if (kp < 7) LOAD(kp + 1);
#pragma unroll
        for (int kk = 0; kk < 16; ++kk) {
            float4 xa = *(const float4*)&xs[cur][kk][r0];
            float4 wa = *(const float4*)&ws[cur][kk][c0];
            float4 wb = *(const float4*)&ws[cur][kk][c0 + 64];
            float xv[4] = {xa.x, xa.y, xa.z, xa.w};
            float wv[8] = {wa.x, wa.y, wa.z, wa.w, wb.x, wb.y, wb.z, wb.w};
#pragma unroll
            for (int i = 0; i < 4; ++i)
#pragma unroll
                for (int j = 0; j < 8; ++j)
                    acc[i][j] += xv[i] * wv[j];
        }
        if (kp < 7) {
            __syncthreads();
            WRITE(cur ^ 1);
            __syncthreads();
        }
    }

#pragma unroll
    for (int i = 0; i < 4; ++i) {
        int rg = row0 + r0 + i;
        if (rg < NN) {
            *(float4*)(out + (size_t)rg * D + c0) =
                make_float4(acc[i][0], acc[i][1], acc[i][2], acc[i][3]);
            *(float4*)(out + (size_t)rg * D + c0 + 64) =
                make_float4(acc[i][4], acc[i][5], acc[i][6], acc[i][7]);
        }
    }
}

// ---------------- K1: gemm1 (blocks 0..GEMM_BLKS) || hist (rest) ----------------
__global__ __launch_bounds__(256) void k_gemm1_hist(const float* __restrict__ x,
                                                    const float* __restrict__ W1,
                                                    float* __restrict__ bufA,
                                                    const int* __restrict__ dst,
                                                    int* __restrict__ deg) {
    int b = blockIdx.x;
    if (b < GEMM_BLKS) {
        gemm_body(x, W1, nullptr, 0, bufA, b);
    } else {
        int e = (b - GEMM_BLKS) * 256 + threadIdx.x;
        if (e < NE) atomicAdd(&deg[dst[e]], 1);
    }
}

// ---------------- layer-2 GEMM ----------------
__global__ __launch_bounds__(256) void k_gemm(const float* __restrict__ in,
                                              const float* __restrict__ W,
                                              const float* __restrict__ bias_in,
                                              float* __restrict__ out) {
    gemm_body(in, W, bias_in, 1, out, blockIdx.x);
}

// ---------------- K2: scanA (+dinv fused) || bounds ----------------
__global__ __launch_bounds__(256) void k_scanA(const int* __restrict__ deg,
                                               float* __restrict__ dinv,
                                               int* __restrict__ row_ptr,
                                               int* __restrict__ bsum,
                                               const int* __restrict__ batch,
                                               int* __restrict__ gstart) {
    int b = blockIdx.x, tid = threadIdx.x;
    if (b >= NB) {
        int g = (b - NB) * 256 + tid;
        if (g > NG) return;
        if (g == NG) { gstart[NG] = NN; return; }
        int lo = 0, hi = NN;               // first v with batch[v] >= g
        while (lo < hi) {
            int mid = (lo + hi) >> 1;
            if (batch[mid] < g) lo = mid + 1; else hi = mid;
        }
        gstart[g] = lo;
        return;
    }
    __shared__ int sh[256];
    int base = b * SCAN_CHUNK + tid * 8;
    int loc[8];
    int s = 0;
#pragma unroll
    for (int j = 0; j < 8; ++j) {
        int i = base + j;
        int d = (i < NN) ? deg[i] : 0;
        if (i < NN) dinv[i] = rsqrtf((float)(d + 1));   // +1 self-loop
        loc[j] = s;
        s += d;
    }
    sh[tid] = s;
    __syncthreads();
    for (int off = 1; off < 256; off <<= 1) {
        int v = (tid >= off) ? sh[tid - off] : 0;
        __syncthreads();
        sh[tid] += v;
        __syncthreads();
    }
    int excl = (tid == 0) ? 0 : sh[tid - 1];
#pragma unroll
    for (int j = 0; j < 8; ++j) {
        int i = base + j;
        if (i < NN) row_ptr[i] = excl + loc[j];
    }
    if (tid == 255) bsum[b] = sh[255];
}

// ---------------- K3: scanC with inline block-sum prefix (scanB merged) ----------------
__global__ __launch_bounds__(256) void k_scanC(int* __restrict__ row_ptr,
                                               const int* __restrict__ bsum,
                                               int* __restrict__ fill) {
    __shared__ int sb[64];
    int tid = threadIdx.x;
    if (tid < NB) sb[tid] = bsum[tid];
    __syncthreads();
    int chunk = (blockIdx.x * 256) / SCAN_CHUNK;
    int pre = 0;
    for (int b = 0; b < chunk; ++b) pre += sb[b];   // uniform LDS broadcast
    int i = blockIdx.x * 256 + tid;
    if (i < NN) {
        int r = row_ptr[i] + pre;
        row_ptr[i] = r;
        fill[i] = r;
    }
    if (i == 0) row_ptr[NN] = NE;
}

// ---------------- CSR fill: csr[pos] = {src, norm} ----------------
__global__ __launch_bounds__(256) void k_fill(const int* __restrict__ src,
                                              const int* __restrict__ dst,
                                              const float* __restrict__ dinv,
                                              int* __restrict__ fill,
                                              int2* __restrict__ csr) {
    int e = blockIdx.x * 256 + threadIdx.x;
    if (e >= NE) return;
    int s = src[e], d = dst[e];
    float nrm = dinv[s] * dinv[d];
    int pos = atomicAdd(&fill[d], 1);
    csr[pos] = make_int2(s, __float_as_int(nrm));
}

// ---------------- gather: agg[v] = h[v]*dinv[v]^2 + sum_in h[s]*norm ----------------
__global__ __launch_bounds__(256) void k_gather(const float* __restrict__ h,
                                                const int* __restrict__ row_ptr,
                                                const int2* __restrict__ csr,
                                                const float* __restrict__ dinv,
                                                float* __restrict__ agg) {
    int t = blockIdx.x * 256 + threadIdx.x;   // NN*32 threads
    int v = t >> 5;
    if (v >= NN) return;
    int c = (t & 31) * 4;

    float di = dinv[v];
    float sl = di * di;
    float4 acc = *(const float4*)(h + (size_t)v * D + c);
    acc.x *= sl; acc.y *= sl; acc.z *= sl; acc.w *= sl;

    int p   = row_ptr[v];
    int end = row_ptr[v + 1];
    for (; p + 3 < end; p += 4) {
        int2 e0 = csr[p], e1 = csr[p + 1], e2 = csr[p + 2], e3 = csr[p + 3];
        float n0 = __int_as_float(e0.y);
        float n1 = __int_as_float(e1.y);
        float n2 = __int_as_float(e2.y);
        float n3 = __int_as_float(e3.y);
        float4 h0 = *(const float4*)(h + (size_t)e0.x * D + c);
        float4 h1 = *(const float4*)(h + (size_t)e1.x * D + c);
        float4 h2 = *(const float4*)(h + (size_t)e2.x * D + c);
        float4 h3 = *(const float4*)(h + (size_t)e3.x * D + c);
        acc.x += h0.x * n0; acc.y += h0.y * n0; acc.z += h0.z * n0; acc.w += h0.w * n0;
        acc.x += h1.x * n1; acc.y += h1.y * n1; acc.z += h1.z * n1; acc.w += h1.w * n1;
        acc.x += h2.x * n2; acc.y += h2.y * n2; acc.z += h2.z * n2; acc.w += h2.w * n2;
        acc.x += h3.x * n3; acc.y += h3.y * n3; acc.z += h3.z * n3; acc.w += h3.w * n3;
    }
    for (; p < end; ++p) {
        int2 e0 = csr[p];
        float n0 = __int_as_float(e0.y);
        float4 h0 = *(const float4*)(h + (size_t)e0.x * D + c);
        acc.x += h0.x * n0; acc.y += h0.y * n0; acc.z += h0.z * n0; acc.w += h0.w * n0;
    }
    *(float4*)(agg + (size_t)v * D + c) = acc;
}

// ---------------- fused pool + classifier (block per graph) ----------------
__global__ __launch_bounds__(128) void k_poolcls(const float* __restrict__ agg,
                                                 const float* __restrict__ b2,
                                                 const int* __restrict__ gstart,
                                                 const float* __restrict__ Wc,
                                                 const float* __restrict__ bc,
                                                 float* __restrict__ out) {
    int g = blockIdx.x;
    int c = threadIdx.x;
    int v0 = gstart[g], v1 = gstart[g + 1];
    float bb = b2[c];
    float acc = 0.f;
    int v = v0;
    for (; v + 3 < v1; v += 4) {
        float x0 = agg[(size_t)(v + 0) * D + c];
        float x1 = agg[(size_t)(v + 1) * D + c];
        float x2 = agg[(size_t)(v + 2) * D + c];
        float x3 = agg[(size_t)(v + 3) * D + c];
        acc += fmaxf(x0 + bb, 0.f) + fmaxf(x1 + bb, 0.f)
             + fmaxf(x2 + bb, 0.f) + fmaxf(x3 + bb, 0.f);
    }
    for (; v < v1; ++v)
        acc += fmaxf(agg[(size_t)v * D + c] + bb, 0.f);

    float inv = 1.0f / fmaxf((float)(v1 - v0), 1.0f);
    float pv = acc * inv;

    __shared__ float red[2][128];
    red[0][c] = pv * Wc[c * 2 + 0];
    red[1][c] = pv * Wc[c * 2 + 1];
    __syncthreads();
    if (c < 64) {
        float s = red[0][c] + red[0][c + 64];
        for (int off = 32; off; off >>= 1) s += __shfl_down(s, off);
        if (c == 0) out[g * 2 + 0] = s + bc[0];
    } else {
        int l = c - 64;
        float s = red[1][l] + red[1][l + 64];
        for (int off = 32; off; off >>= 1) s += __shfl_down(s, off);
        if (l == 0) out[g * 2 + 1] = s + bc[1];
    }
}

extern "C" void kernel_launch(void* const* d_in, const int* in_sizes, int n_in,
                              void* d_out, int out_size, void* d_ws, size_t ws_size,
                              hipStream_t stream) {
    const float* x     = (const float*)d_in[0];
    const int*   ei    = (const int*)d_in[1];
    const int*   batch = (const int*)d_in[2];
    const float* W1    = (const float*)d_in[3];
    const float* b1    = (const float*)d_in[4];
    const float* W2    = (const float*)d_in[5];
    const float* b2    = (const float*)d_in[6];
    const float* Wc    = (const float*)d_in[7];
    const float* bc    = (const float*)d_in[8];
    float* out = (float*)d_out;

    const int* src = ei;            // edge_index[0]
    const int* dst = ei + NE;       // edge_index[1]

    char* p = (char*)d_ws;
    int*   deg_i   = (int*)p;    p += 100352 * 4;
    float* dinv    = (float*)p;  p += 100352 * 4;
    int*   row_ptr = (int*)p;    p += 100352 * 4;   // NN+1 fits
    int*   fillc   = (int*)p;    p += 100352 * 4;
    int*   bsum    = (int*)p;    p += 256 * 4;
    int*   gstart  = (int*)p;    p += 1056 * 4;     // NG+1
    int2*  csr     = (int2*)p;   p += (size_t)NE * 8;
    float* bufA    = (float*)p;  p += (size_t)NN * D * 4;
    float* bufB    = (float*)p;  p += (size_t)NN * D * 4;

    hipMemsetAsync(deg_i, 0, 100352 * 4, stream);

    // K1: layer-1 GEMM || degree histogram (independent work, one launch)
    k_gemm1_hist<<<GEMM_BLKS + HIST_BLKS, 256, 0, stream>>>(x, W1, bufA, dst, deg_i);
    // K2: scan phase A (+dinv) || graph bounds
    k_scanA<<<NB + BOUNDS_BLKS, 256, 0, stream>>>(deg_i, dinv, row_ptr, bsum, batch, gstart);
    // K3: scan finalize (block-sum prefix inline)
    k_scanC<<<(NN + 255) / 256, 256, 0, stream>>>(row_ptr, bsum, fillc);
    // K4: CSR fill
    k_fill<<<HIST_BLKS, 256, 0, stream>>>(src, dst, dinv, fillc, csr);

    // layer 1 gather
    k_gather<<<NN * 32 / 256, 256, 0, stream>>>(bufA, row_ptr, csr, dinv, bufB);

    // layer 2 (bias1+relu fused into gemm load)
    k_gemm<<<GEMM_BLKS, 256, 0, stream>>>(bufB, W2, b1, bufA);
    k_gather<<<NN * 32 / 256, 256, 0, stream>>>(bufA, row_ptr, csr, dinv, bufB);

    // fused pooling (bias2+relu) + classifier
    k_poolcls<<<NG, 128, 0, stream>>>(bufB, b2, gstart, Wc, bc, out);
}